// Round 10
// baseline (362.990 us; speedup 1.0000x reference)
//
#include <hip/hip_runtime.h>
#include <hip/hip_bf16.h>
#include <math.h>

#define GN 12288
#define GE 196608
#define GK 1433
#define GC 32
#define CAP 64        // fixed CSR capacity/node; max degree ~38
#define NGRP 192      // k-groups of 8, zero-padded to 1536 = 3 sweeps * 512
#define GEMMB 768     // 16 rows per gemm tile
#define NEDGE 8       // hierarchical edge blocks (LDS histogram)
#define EPB   24576   // edges per edge block: 8*24576 = GE exactly
#define NBIN  4096    // histogram bins per pass (3 passes cover GN)
#define PACKB 24      // 24*256 = 6144 = NGRP*GC exactly
#define ZEROB 96      // 96*256 = 24576 = 2*GN exactly
#define XSTR 516      // LDS row stride (floats): 512+4 pad, 16B-aligned

typedef __attribute__((ext_vector_type(8))) short bf16x8;
typedef __attribute__((ext_vector_type(4))) float f32x4;
typedef float f32x4a __attribute__((ext_vector_type(4), aligned(4)));

static __device__ inline unsigned short f2bf(float f) {
    unsigned u = __float_as_uint(f);
    return (unsigned short)((u + 0x7fffu + ((u >> 16) & 1u)) >> 16);
}
static __device__ inline float bf2f(unsigned short h) {
    return __uint_as_float(((unsigned)h) << 16);
}
static __device__ inline unsigned short f2bf_hw(float f) {
    return __builtin_bit_cast(unsigned short, __float2bfloat16(f));
}

// ---------------- prep: zero cnt/deg + pack W1 -> bf16 hi/lo fragments ------
__global__ __launch_bounds__(256) void prep_kernel(const float* __restrict__ W1,
                                                   unsigned* __restrict__ zbuf,
                                                   unsigned short* __restrict__ Whb,
                                                   unsigned short* __restrict__ Wlb) {
    int t = threadIdx.x, b = blockIdx.x;
    if (b < PACKB) {
        int idx = b * 256 + t;           // idx = g*32 + c
        int g = idx >> 5, c = idx & 31;
        bf16x8 vh, vl;
        #pragma unroll
        for (int j = 0; j < 8; ++j) {
            int k = g * 8 + j;
            float f = (k < GK) ? W1[(size_t)k * GC + c] : 0.f;
            unsigned short hh = f2bf(f);
            vh[j] = (short)hh;
            vl[j] = (short)f2bf(f - bf2f(hh));
        }
        *(bf16x8*)(Whb + (size_t)idx * 8) = vh;
        *(bf16x8*)(Wlb + (size_t)idx * 8) = vl;
    } else {
        int idx = (b - PACKB) * 256 + t; // zero cnt+deg (contiguous, 2*GN words)
        zbuf[idx] = 0u;
    }
}

// ---------------- fused: edge blocks (0..7, LDS-histogram) + gemm ----------
// R9 post-mortem: branch-scoped __shared__ arrays were SUMMED (107 KB/block)
// -> 1 block/CU -> occupancy collapse. Fix: ONE 33 KB shared buffer, aliased:
//   gemm  -> xs[16][XSTR] (33024 B, R6-proven body unchanged)
//   edge  -> lc[4096] (16 KB) + base16[4096] (8 KB), 3 node-range passes
// Edge histogram cuts device-scope atomics 393K -> ~170K (one per distinct
// node per block); disjoint [base,base+c) ranges keep adjF race-free.
__global__ __launch_bounds__(256) void fused_kernel(const float* __restrict__ x,
                                                    const int* __restrict__ ei,
                                                    const unsigned short* __restrict__ Whb,
                                                    const unsigned short* __restrict__ Wlb,
                                                    float* __restrict__ xw,
                                                    unsigned* __restrict__ cnt,
                                                    unsigned* __restrict__ deg,
                                                    unsigned* __restrict__ adjF) {
    int t = threadIdx.x, bid = blockIdx.x;
    __shared__ __align__(16) float smem[16 * XSTR];   // 33024 B, shared by both roles

    if (bid < NEDGE) {
        // ---- hierarchical edge build (aliased LDS: 24 KB of the 33 KB) ----
        unsigned* lc = (unsigned*)smem;                         // 4096 * 4 = 16 KB
        unsigned short* b16 = (unsigned short*)(smem + NBIN);   // 4096 * 2 =  8 KB
        int e0 = bid * EPB;

        // src: count -> merge(+base) -> place, per node range
        for (int p = 0; p < 3; ++p) {
            int lo = p * NBIN;
            for (int i = t; i < NBIN; i += 256) lc[i] = 0u;
            __syncthreads();
            for (int k = t; k < EPB; k += 256) {
                unsigned r = (unsigned)(ei[e0 + k] - lo);
                if (r < (unsigned)NBIN) atomicAdd(&lc[r], 1u);
            }
            __syncthreads();
            for (int i = t; i < NBIN; i += 256) {
                unsigned c = lc[i];
                if (c) b16[i] = (unsigned short)atomicAdd(&cnt[lo + i], c);
            }
            __syncthreads();
            for (int i = t; i < NBIN; i += 256) lc[i] = 0u;
            __syncthreads();
            for (int k = t; k < EPB; k += 256) {
                int s = ei[e0 + k];
                unsigned r = (unsigned)(s - lo);
                if (r < (unsigned)NBIN) {
                    int d = ei[GE + e0 + k];
                    unsigned pth = (unsigned)b16[r] + atomicAdd(&lc[r], 1u);
                    if (pth < CAP) adjF[(unsigned)s * CAP + pth] = (unsigned)d;
                }
            }
            __syncthreads();
        }
        // dst: count -> merge into deg, per node range
        for (int p = 0; p < 3; ++p) {
            int lo = p * NBIN;
            for (int i = t; i < NBIN; i += 256) lc[i] = 0u;
            __syncthreads();
            for (int k = t; k < EPB; k += 256) {
                unsigned r = (unsigned)(ei[GE + e0 + k] - lo);
                if (r < (unsigned)NBIN) atomicAdd(&lc[r], 1u);
            }
            __syncthreads();
            for (int i = t; i < NBIN; i += 256) {
                unsigned c = lc[i];
                if (c) atomicAdd(&deg[lo + i], c);
            }
            __syncthreads();
        }
        return;
    }

    // ---- gemm tile (R6 body, unchanged; xs aliases smem) ----
    int gb = bid - NEDGE;
    float (*xs)[XSTR] = (float (*)[XSTR])smem;
    int lane = t & 63, w = t >> 6;
    int quad = lane >> 4, l15 = lane & 15;
    const float* xb = x + (size_t)gb * 16 * GK;
    f32x4 acc0 = {}, acc1 = {};
    int r0 = t >> 7;            // 0 or 1
    int pos = t & 127;          // 4-float column group
    f32x4 g0, g1, g2, g3, g4, g5, g6, g7;

#define LOADG(K0) { \
    const float* pp = xb + (size_t)r0 * GK + (K0) + pos * 4; \
    g0 = *(const f32x4a*)(pp); \
    g1 = *(const f32x4a*)(pp + 2 * GK); \
    g2 = *(const f32x4a*)(pp + 4 * GK); \
    g3 = *(const f32x4a*)(pp + 6 * GK); \
    g4 = *(const f32x4a*)(pp + 8 * GK); \
    g5 = *(const f32x4a*)(pp + 10 * GK); \
    g6 = *(const f32x4a*)(pp + 12 * GK); \
    g7 = *(const f32x4a*)(pp + 14 * GK); }

#define LG1(DST, ROFF, PP, KB) { \
    const float* q_ = (PP) + (size_t)(ROFF) * GK; \
    if ((KB) + 4 <= GK) DST = *(const f32x4a*)q_; \
    else { \
        DST[0] = ((KB) + 0 < GK) ? q_[0] : 0.f; \
        DST[1] = ((KB) + 1 < GK) ? q_[1] : 0.f; \
        DST[2] = ((KB) + 2 < GK) ? q_[2] : 0.f; \
        DST[3] = ((KB) + 3 < GK) ? q_[3] : 0.f; } }

#define LOADG_TAIL(K0) { \
    const float* pp = xb + (size_t)r0 * GK + (K0) + pos * 4; \
    int kb = (K0) + pos * 4; \
    LG1(g0, 0, pp, kb)  LG1(g1, 2, pp, kb)  LG1(g2, 4, pp, kb)  LG1(g3, 6, pp, kb) \
    LG1(g4, 8, pp, kb)  LG1(g5, 10, pp, kb) LG1(g6, 12, pp, kb) LG1(g7, 14, pp, kb) }

#define STOREL() { \
    float* lp = &xs[r0][pos * 4]; \
    *(f32x4*)(lp)              = g0; \
    *(f32x4*)(lp + 2 * XSTR)   = g1; \
    *(f32x4*)(lp + 4 * XSTR)   = g2; \
    *(f32x4*)(lp + 6 * XSTR)   = g3; \
    *(f32x4*)(lp + 8 * XSTR)   = g4; \
    *(f32x4*)(lp + 10 * XSTR)  = g5; \
    *(f32x4*)(lp + 12 * XSTR)  = g6; \
    *(f32x4*)(lp + 14 * XSTR)  = g7; }

#define COMPUTE(S) { \
    _Pragma("unroll") \
    for (int c = 0; c < 4; ++c) { \
        int kl = w * 128 + c * 32 + quad * 8; \
        const float* ap = &xs[l15][kl]; \
        f32x4 x0 = *(const f32x4*)ap; \
        f32x4 x1 = *(const f32x4*)(ap + 4); \
        bf16x8 ah, al; \
        _Pragma("unroll") for (int j = 0; j < 4; ++j) { \
            unsigned short hh = f2bf_hw(x0[j]); \
            ah[j] = (short)hh; al[j] = (short)f2bf_hw(x0[j] - bf2f(hh)); } \
        _Pragma("unroll") for (int j = 0; j < 4; ++j) { \
            unsigned short hh = f2bf_hw(x1[j]); \
            ah[4 + j] = (short)hh; al[4 + j] = (short)f2bf_hw(x1[j] - bf2f(hh)); } \
        int gg = (S) * 64 + w * 16 + c * 4 + quad; \
        bf16x8 H0 = *(const bf16x8*)(Whb + (size_t)gg * 256 + l15 * 8); \
        bf16x8 H1 = *(const bf16x8*)(Whb + (size_t)gg * 256 + 128 + l15 * 8); \
        bf16x8 L0 = *(const bf16x8*)(Wlb + (size_t)gg * 256 + l15 * 8); \
        bf16x8 L1 = *(const bf16x8*)(Wlb + (size_t)gg * 256 + 128 + l15 * 8); \
        acc0 = __builtin_amdgcn_mfma_f32_16x16x32_bf16(ah, H0, acc0, 0, 0, 0); \
        acc1 = __builtin_amdgcn_mfma_f32_16x16x32_bf16(ah, H1, acc1, 0, 0, 0); \
        acc0 = __builtin_amdgcn_mfma_f32_16x16x32_bf16(ah, L0, acc0, 0, 0, 0); \
        acc1 = __builtin_amdgcn_mfma_f32_16x16x32_bf16(ah, L1, acc1, 0, 0, 0); \
        acc0 = __builtin_amdgcn_mfma_f32_16x16x32_bf16(al, H0, acc0, 0, 0, 0); \
        acc1 = __builtin_amdgcn_mfma_f32_16x16x32_bf16(al, H1, acc1, 0, 0, 0); \
    } }

    LOADG(0);
    STOREL();
    __syncthreads();
    LOADG(512);            // issue-early (T14): hides under COMPUTE(0)
    COMPUTE(0);
    __syncthreads();
    STOREL();
    __syncthreads();
    LOADG_TAIL(1024);
    COMPUTE(1);
    __syncthreads();
    STOREL();
    __syncthreads();
    COMPUTE(2);
    __syncthreads();

    float (*red)[16][32] = (float (*)[16][32])(&xs[0][0]);
    #pragma unroll
    for (int i = 0; i < 4; ++i) {
        red[w][quad * 4 + i][l15] = acc0[i];
        red[w][quad * 4 + i][16 + l15] = acc1[i];
    }
    __syncthreads();
    int rr0 = t >> 5, cc0 = t & 31;
    float s0 = red[0][rr0][cc0] + red[1][rr0][cc0] + red[2][rr0][cc0] + red[3][rr0][cc0];
    int rr1 = rr0 + 8;
    float s1 = red[0][rr1][cc0] + red[1][rr1][cc0] + red[2][rr1][cc0] + red[3][rr1][cc0];
    xw[(size_t)gb * 512 + t] = s0;
    xw[(size_t)gb * 512 + 256 + t] = s1;
}

// ---------------- GCN gather -> h (inline rsqrt of deg) ----------------
__global__ __launch_bounds__(256) void gcn_kernel(const float* __restrict__ xw,
                                                  const unsigned* __restrict__ deg,
                                                  const unsigned* __restrict__ cnt,
                                                  const unsigned* __restrict__ adjF,
                                                  const float* __restrict__ b1,
                                                  float* __restrict__ h) {
    int w = threadIdx.x >> 6;
    int lane = threadIdx.x & 63;
    int i = blockIdx.x * 4 + w;
    int f = lane & 31, half = lane >> 5;
    unsigned cl = min(cnt[i], (unsigned)CAP);
    const unsigned* ai = adjF + (unsigned)i * CAP;
    float acc = 0.f;
    for (unsigned j = half; j < cl; j += 8) {
        unsigned lim = cl - 1;
        unsigned j1 = j + 2, j2 = j + 4, j3 = j + 6;
        unsigned d0 = ai[j];
        unsigned d1 = ai[min(j1, lim)];
        unsigned d2 = ai[min(j2, lim)];
        unsigned d3 = ai[min(j3, lim)];
        float m1 = j1 < cl ? 1.f : 0.f;
        float m2 = j2 < cl ? 1.f : 0.f;
        float m3 = j3 < cl ? 1.f : 0.f;
        acc += xw[(size_t)d0 * GC + f] * rsqrtf((float)(deg[d0] + 1u));
        acc += m1 * xw[(size_t)d1 * GC + f] * rsqrtf((float)(deg[d1] + 1u));
        acc += m2 * xw[(size_t)d2 * GC + f] * rsqrtf((float)(deg[d2] + 1u));
        acc += m3 * xw[(size_t)d3 * GC + f] * rsqrtf((float)(deg[d3] + 1u));
    }
    acc += __shfl_xor(acc, 32, 64);
    float disi = rsqrtf((float)(deg[i] + 1u));
    float v = b1[f] + disi * (disi * xw[(size_t)i * GC + f] + acc);
    if (half == 0) h[(size_t)i * GC + f] = fmaxf(v, 0.f);
}

// ---------------- SAGE gather + fused head ----------------
__global__ __launch_bounds__(256) void sage_kernel(const float* __restrict__ h,
                                                   const unsigned* __restrict__ cnt,
                                                   const unsigned* __restrict__ adjF,
                                                   const float* __restrict__ Wl,
                                                   const float* __restrict__ bl,
                                                   const float* __restrict__ Wr,
                                                   const float* __restrict__ br,
                                                   const float* __restrict__ W3,
                                                   const float* __restrict__ b3,
                                                   float* __restrict__ out) {
    __shared__ float sh[4][64];
    __shared__ float so[4][16];
    int w = threadIdx.x >> 6, lane = threadIdx.x & 63;
    int i = blockIdx.x * 4 + w;
    int f = lane & 31, half = lane >> 5;
    unsigned ci = cnt[i];
    unsigned cl = min(ci, (unsigned)CAP);
    const unsigned* ai = adjF + (unsigned)i * CAP;
    float acc = 0.f;
    for (unsigned j = half; j < cl; j += 8) {
        unsigned lim = cl - 1;
        unsigned j1 = j + 2, j2 = j + 4, j3 = j + 6;
        unsigned d0 = ai[j];
        unsigned d1 = ai[min(j1, lim)];
        unsigned d2 = ai[min(j2, lim)];
        unsigned d3 = ai[min(j3, lim)];
        float m1 = j1 < cl ? 1.f : 0.f;
        float m2 = j2 < cl ? 1.f : 0.f;
        float m3 = j3 < cl ? 1.f : 0.f;
        acc += h[(size_t)d0 * GC + f];
        acc += m1 * h[(size_t)d1 * GC + f];
        acc += m2 * h[(size_t)d2 * GC + f];
        acc += m3 * h[(size_t)d3 * GC + f];
    }
    acc += __shfl_xor(acc, 32, 64);
    float agg = ci ? acc / (float)ci : 0.f;
    float hv = h[(size_t)i * GC + f];
    if (half == 0) { sh[w][f] = hv; sh[w][32 + f] = agg; }
    __syncthreads();
    int c = lane;
    float hid = 0.f;
    if (c < 16) {
        hid = bl[c] + br[c];
        #pragma unroll
        for (int ff = 0; ff < 32; ++ff)
            hid += sh[w][ff] * Wl[ff * 16 + c] + sh[w][32 + ff] * Wr[ff * 16 + c];
        hid = fmaxf(hid, 0.f);
    }
    float n2 = hid * hid;
    n2 += __shfl_xor(n2, 1, 64);
    n2 += __shfl_xor(n2, 2, 64);
    n2 += __shfl_xor(n2, 4, 64);
    n2 += __shfl_xor(n2, 8, 64);
    float o = hid / (sqrtf(n2) + 1e-6f);
    if (c < 16) so[w][c] = o;
    __syncthreads();
    float logit = -INFINITY;
    if (lane < 7) {
        logit = b3[lane];
        #pragma unroll
        for (int cc = 0; cc < 16; ++cc) logit += so[w][cc] * W3[cc * 7 + lane];
    }
    float m = logit;
    m = fmaxf(m, __shfl_xor(m, 1, 64));
    m = fmaxf(m, __shfl_xor(m, 2, 64));
    m = fmaxf(m, __shfl_xor(m, 4, 64));
    float e = expf(logit - m);
    float s = e;
    s += __shfl_xor(s, 1, 64);
    s += __shfl_xor(s, 2, 64);
    s += __shfl_xor(s, 4, 64);
    if (lane < 7) out[(size_t)i * 7 + lane] = e / s;
}

extern "C" void kernel_launch(void* const* d_in, const int* in_sizes, int n_in,
                              void* d_out, int out_size, void* d_ws, size_t ws_size,
                              hipStream_t stream) {
    const float* x  = (const float*)d_in[0];
    const int*   ei = (const int*)d_in[1];
    const float* W1 = (const float*)d_in[2];
    const float* b1 = (const float*)d_in[3];
    const float* Wl = (const float*)d_in[4];
    const float* bl = (const float*)d_in[5];
    const float* Wr = (const float*)d_in[6];
    const float* br = (const float*)d_in[7];
    const float* W3 = (const float*)d_in[8];
    const float* b3 = (const float*)d_in[9];
    float* out = (float*)d_out;

    char* ws = (char*)d_ws;
    const size_t S = (size_t)GN * GC * 4;                  // 1.57 MB
    float*    xw   = (float*)(ws);
    unsigned* cnt  = (unsigned*)(ws + S);
    unsigned* deg  = cnt + GN;
    float*    h    = (float*)(deg + GN);
    unsigned* adjF = (unsigned*)((char*)h + S);            // GN*CAP*4 = 3 MB
    unsigned short* Whb = (unsigned short*)((char*)adjF + (size_t)GN * CAP * 4);
    unsigned short* Wlb = Whb + (size_t)NGRP * GC * 8;     // 98304 B each

    prep_kernel<<<PACKB + ZEROB, 256, 0, stream>>>(W1, cnt, Whb, Wlb);
    fused_kernel<<<NEDGE + GEMMB, 256, 0, stream>>>(x, ei, Whb, Wlb, xw, cnt, deg, adjF);
    gcn_kernel<<<GN / 4, 256, 0, stream>>>(xw, deg, cnt, adjF, b1, h);
    sage_kernel<<<GN / 4, 256, 0, stream>>>(h, cnt, adjF, Wl, bl, Wr, br, W3, b3, out);
}

// Round 11
// 153.642 us; speedup vs baseline: 2.3626x; 2.3626x over previous
//
#include <hip/hip_runtime.h>
#include <hip/hip_bf16.h>
#include <math.h>

#define GN 12288
#define GE 196608
#define GK 1433
#define GC 32
#define CAP 64        // fixed CSR capacity/node; max degree ~38
#define NGRP 192      // k-groups of 8, zero-padded to 1536 = 6 sweeps * 256
#define GEMMB 768     // 16 rows per gemm tile
#define EDGEB 768     // 768*256 = 196608 = GE exactly (flat, R6-proven)
#define PACKB 24      // 24*256 = 6144 = NGRP*GC exactly
#define ZEROB 96      // 96*256 = 24576 = 2*GN exactly
#define XSTR2 260     // LDS row stride (floats): 256+4 pad -> bank-balanced, 16B-aligned

typedef __attribute__((ext_vector_type(8))) short bf16x8;
typedef __attribute__((ext_vector_type(4))) float f32x4;
typedef float f32x4a __attribute__((ext_vector_type(4), aligned(4)));

static __device__ inline unsigned short f2bf(float f) {
    unsigned u = __float_as_uint(f);
    return (unsigned short)((u + 0x7fffu + ((u >> 16) & 1u)) >> 16);
}
static __device__ inline float bf2f(unsigned short h) {
    return __uint_as_float(((unsigned)h) << 16);
}
static __device__ inline unsigned short f2bf_hw(float f) {
    return __builtin_bit_cast(unsigned short, __float2bfloat16(f));
}

// ---------------- prep: zero cnt/deg + pack W1 -> bf16 hi/lo fragments ------
__global__ __launch_bounds__(256) void prep_kernel(const float* __restrict__ W1,
                                                   unsigned* __restrict__ zbuf,
                                                   unsigned short* __restrict__ Whb,
                                                   unsigned short* __restrict__ Wlb) {
    int t = threadIdx.x, b = blockIdx.x;
    if (b < PACKB) {
        int idx = b * 256 + t;           // idx = g*32 + c
        int g = idx >> 5, c = idx & 31;
        bf16x8 vh, vl;
        #pragma unroll
        for (int j = 0; j < 8; ++j) {
            int k = g * 8 + j;
            float f = (k < GK) ? W1[(size_t)k * GC + c] : 0.f;
            unsigned short hh = f2bf(f);
            vh[j] = (short)hh;
            vl[j] = (short)f2bf(f - bf2f(hh));
        }
        *(bf16x8*)(Whb + (size_t)idx * 8) = vh;
        *(bf16x8*)(Wlb + (size_t)idx * 8) = vl;
    } else {
        int idx = (b - PACKB) * 256 + t; // zero cnt+deg (contiguous, 2*GN words)
        zbuf[idx] = 0u;
    }
}

// ---------------- fused: gemm (0..767) + flat edge build (768..1535) --------
// R10 post-mortem: 8-block histogram = all edge work on 3% of the machine
// (fused 248us, occ 2.6%). REVERTED to R6's flat one-edge-per-thread build
// (~9us, hidden under gemm — R2 measurement). Gemm upgraded: 6 sweeps of 256
// cols, TWO LDS buffers (2x16x260f = 33280 B, same footprint) -> STOREL(s+1)
// writes the buffer COMPUTE(s) isn't reading -> ONE barrier per sweep (was 2),
// loads issued a full compute-phase ahead. Row stride 260: b128 reads/writes
// hit the 8-dword/bank minimum (256 would be 2x conflicted).
__global__ __launch_bounds__(256) void fused_kernel(const float* __restrict__ x,
                                                    const int* __restrict__ ei,
                                                    const unsigned short* __restrict__ Whb,
                                                    const unsigned short* __restrict__ Wlb,
                                                    float* __restrict__ xw,
                                                    unsigned* __restrict__ cnt,
                                                    unsigned* __restrict__ deg,
                                                    unsigned* __restrict__ adjF) {
    int t = threadIdx.x, bid = blockIdx.x;

    if (bid >= GEMMB) {
        // ---- flat graph build: one edge per thread (R6-proven) ----
        int e = (bid - GEMMB) * 256 + t;
        int src = ei[e];
        int dst = ei[GE + e];
        unsigned pos = atomicAdd(&cnt[src], 1u);
        if (pos < CAP) adjF[(unsigned)src * CAP + pos] = (unsigned)dst;
        atomicAdd(&deg[dst], 1u);
        return;
    }

    // ---- gemm tile: 16 rows, 6x256-col sweeps, double-buffered LDS ----
    __shared__ __align__(16) float smem[2 * 16 * XSTR2];   // 33280 B
    float (*xs)[16][XSTR2] = (float (*)[16][XSTR2])smem;
    int lane = t & 63, w = t >> 6;
    int quad = lane >> 4, l15 = lane & 15;
    const float* xb = x + (size_t)bid * 16 * GK;
    f32x4 acc0 = {}, acc1 = {};
    int r0w = t >> 6;           // == wave: rows {w, w+4, w+8, w+12}
    int posc = t & 63;          // 4-float column group within sweep
    f32x4 gA0, gA1, gA2, gA3, gB0, gB1, gB2, gB3;

#define LOADG(G0, G1, G2, G3, S) { \
    const float* pp = xb + (size_t)r0w * GK + (S) * 256 + posc * 4; \
    G0 = *(const f32x4a*)(pp); \
    G1 = *(const f32x4a*)(pp + 4 * GK); \
    G2 = *(const f32x4a*)(pp + 8 * GK); \
    G3 = *(const f32x4a*)(pp + 12 * GK); }

#define LG1(DST, ROFF, PP, KB) { \
    const float* q_ = (PP) + (size_t)(ROFF) * GK; \
    if ((KB) + 4 <= GK) DST = *(const f32x4a*)q_; \
    else { \
        DST[0] = ((KB) + 0 < GK) ? q_[0] : 0.f; \
        DST[1] = ((KB) + 1 < GK) ? q_[1] : 0.f; \
        DST[2] = ((KB) + 2 < GK) ? q_[2] : 0.f; \
        DST[3] = ((KB) + 3 < GK) ? q_[3] : 0.f; } }

#define LOADGT(G0, G1, G2, G3, S) { \
    const float* pp = xb + (size_t)r0w * GK + (S) * 256 + posc * 4; \
    int kb = (S) * 256 + posc * 4; \
    LG1(G0, 0, pp, kb)  LG1(G1, 4, pp, kb)  LG1(G2, 8, pp, kb)  LG1(G3, 12, pp, kb) }

#define STOREL(G0, G1, G2, G3, BUF) { \
    float* lp = &xs[BUF][r0w][posc * 4]; \
    *(f32x4*)(lp)               = G0; \
    *(f32x4*)(lp + 4 * XSTR2)   = G1; \
    *(f32x4*)(lp + 8 * XSTR2)   = G2; \
    *(f32x4*)(lp + 12 * XSTR2)  = G3; }

#define COMPUTE(S, BUF) { \
    _Pragma("unroll") \
    for (int c = 0; c < 2; ++c) { \
        int kl = w * 64 + c * 32 + quad * 8; \
        const float* ap = &xs[BUF][l15][kl]; \
        f32x4 x0 = *(const f32x4*)ap; \
        f32x4 x1 = *(const f32x4*)(ap + 4); \
        bf16x8 ah, al; \
        _Pragma("unroll") for (int j = 0; j < 4; ++j) { \
            unsigned short hh = f2bf_hw(x0[j]); \
            ah[j] = (short)hh; al[j] = (short)f2bf_hw(x0[j] - bf2f(hh)); } \
        _Pragma("unroll") for (int j = 0; j < 4; ++j) { \
            unsigned short hh = f2bf_hw(x1[j]); \
            ah[4 + j] = (short)hh; al[4 + j] = (short)f2bf_hw(x1[j] - bf2f(hh)); } \
        int gg = (S) * 32 + w * 8 + c * 4 + quad; \
        bf16x8 H0 = *(const bf16x8*)(Whb + (size_t)gg * 256 + l15 * 8); \
        bf16x8 H1 = *(const bf16x8*)(Whb + (size_t)gg * 256 + 128 + l15 * 8); \
        bf16x8 L0 = *(const bf16x8*)(Wlb + (size_t)gg * 256 + l15 * 8); \
        bf16x8 L1 = *(const bf16x8*)(Wlb + (size_t)gg * 256 + 128 + l15 * 8); \
        acc0 = __builtin_amdgcn_mfma_f32_16x16x32_bf16(ah, H0, acc0, 0, 0, 0); \
        acc1 = __builtin_amdgcn_mfma_f32_16x16x32_bf16(ah, H1, acc1, 0, 0, 0); \
        acc0 = __builtin_amdgcn_mfma_f32_16x16x32_bf16(ah, L0, acc0, 0, 0, 0); \
        acc1 = __builtin_amdgcn_mfma_f32_16x16x32_bf16(ah, L1, acc1, 0, 0, 0); \
        acc0 = __builtin_amdgcn_mfma_f32_16x16x32_bf16(al, H0, acc0, 0, 0, 0); \
        acc1 = __builtin_amdgcn_mfma_f32_16x16x32_bf16(al, H1, acc1, 0, 0, 0); \
    } }

    // prologue: sweep0 -> buf0, issue sweep1 loads
    LOADG(gA0, gA1, gA2, gA3, 0);
    STOREL(gA0, gA1, gA2, gA3, 0);
    LOADG(gB0, gB1, gB2, gB3, 1);
    __syncthreads();
    // iter 0: loads(s2) | compute(s0,b0) | store(s1->b1)
    LOADG(gA0, gA1, gA2, gA3, 2);
    COMPUTE(0, 0);
    STOREL(gB0, gB1, gB2, gB3, 1);
    __syncthreads();
    // iter 1: loads(s3) | compute(s1,b1) | store(s2->b0)
    LOADG(gB0, gB1, gB2, gB3, 3);
    COMPUTE(1, 1);
    STOREL(gA0, gA1, gA2, gA3, 0);
    __syncthreads();
    // iter 2: loads(s4) | compute(s2,b0) | store(s3->b1)
    LOADG(gA0, gA1, gA2, gA3, 4);
    COMPUTE(2, 0);
    STOREL(gB0, gB1, gB2, gB3, 1);
    __syncthreads();
    // iter 3: loads(s5, tail-guarded) | compute(s3,b1) | store(s4->b0)
    LOADGT(gB0, gB1, gB2, gB3, 5);
    COMPUTE(3, 1);
    STOREL(gA0, gA1, gA2, gA3, 0);
    __syncthreads();
    // iter 4: compute(s4,b0) | store(s5->b1)
    COMPUTE(4, 0);
    STOREL(gB0, gB1, gB2, gB3, 1);
    __syncthreads();
    // iter 5: compute(s5,b1)
    COMPUTE(5, 1);

    // cross-wave reduce: red overlays buf0 (disjoint from buf1 being read)
    float (*red)[16][32] = (float (*)[16][32])smem;
    #pragma unroll
    for (int i = 0; i < 4; ++i) {
        red[w][quad * 4 + i][l15] = acc0[i];
        red[w][quad * 4 + i][16 + l15] = acc1[i];
    }
    __syncthreads();
    int rr0 = t >> 5, cc0 = t & 31;
    float s0 = red[0][rr0][cc0] + red[1][rr0][cc0] + red[2][rr0][cc0] + red[3][rr0][cc0];
    int rr1 = rr0 + 8;
    float s1 = red[0][rr1][cc0] + red[1][rr1][cc0] + red[2][rr1][cc0] + red[3][rr1][cc0];
    xw[(size_t)bid * 512 + t] = s0;
    xw[(size_t)bid * 512 + 256 + t] = s1;
}

// ---------------- GCN gather -> h (inline rsqrt of deg) ----------------
__global__ __launch_bounds__(256) void gcn_kernel(const float* __restrict__ xw,
                                                  const unsigned* __restrict__ deg,
                                                  const unsigned* __restrict__ cnt,
                                                  const unsigned* __restrict__ adjF,
                                                  const float* __restrict__ b1,
                                                  float* __restrict__ h) {
    int w = threadIdx.x >> 6;
    int lane = threadIdx.x & 63;
    int i = blockIdx.x * 4 + w;
    int f = lane & 31, half = lane >> 5;
    unsigned cl = min(cnt[i], (unsigned)CAP);
    const unsigned* ai = adjF + (unsigned)i * CAP;
    float acc = 0.f;
    for (unsigned j = half; j < cl; j += 8) {
        unsigned lim = cl - 1;
        unsigned j1 = j + 2, j2 = j + 4, j3 = j + 6;
        unsigned d0 = ai[j];
        unsigned d1 = ai[min(j1, lim)];
        unsigned d2 = ai[min(j2, lim)];
        unsigned d3 = ai[min(j3, lim)];
        float m1 = j1 < cl ? 1.f : 0.f;
        float m2 = j2 < cl ? 1.f : 0.f;
        float m3 = j3 < cl ? 1.f : 0.f;
        acc += xw[(size_t)d0 * GC + f] * rsqrtf((float)(deg[d0] + 1u));
        acc += m1 * xw[(size_t)d1 * GC + f] * rsqrtf((float)(deg[d1] + 1u));
        acc += m2 * xw[(size_t)d2 * GC + f] * rsqrtf((float)(deg[d2] + 1u));
        acc += m3 * xw[(size_t)d3 * GC + f] * rsqrtf((float)(deg[d3] + 1u));
    }
    acc += __shfl_xor(acc, 32, 64);
    float disi = rsqrtf((float)(deg[i] + 1u));
    float v = b1[f] + disi * (disi * xw[(size_t)i * GC + f] + acc);
    if (half == 0) h[(size_t)i * GC + f] = fmaxf(v, 0.f);
}

// ---------------- SAGE gather + fused head ----------------
__global__ __launch_bounds__(256) void sage_kernel(const float* __restrict__ h,
                                                   const unsigned* __restrict__ cnt,
                                                   const unsigned* __restrict__ adjF,
                                                   const float* __restrict__ Wl,
                                                   const float* __restrict__ bl,
                                                   const float* __restrict__ Wr,
                                                   const float* __restrict__ br,
                                                   const float* __restrict__ W3,
                                                   const float* __restrict__ b3,
                                                   float* __restrict__ out) {
    __shared__ float sh[4][64];
    __shared__ float so[4][16];
    int w = threadIdx.x >> 6, lane = threadIdx.x & 63;
    int i = blockIdx.x * 4 + w;
    int f = lane & 31, half = lane >> 5;
    unsigned ci = cnt[i];
    unsigned cl = min(ci, (unsigned)CAP);
    const unsigned* ai = adjF + (unsigned)i * CAP;
    float acc = 0.f;
    for (unsigned j = half; j < cl; j += 8) {
        unsigned lim = cl - 1;
        unsigned j1 = j + 2, j2 = j + 4, j3 = j + 6;
        unsigned d0 = ai[j];
        unsigned d1 = ai[min(j1, lim)];
        unsigned d2 = ai[min(j2, lim)];
        unsigned d3 = ai[min(j3, lim)];
        float m1 = j1 < cl ? 1.f : 0.f;
        float m2 = j2 < cl ? 1.f : 0.f;
        float m3 = j3 < cl ? 1.f : 0.f;
        acc += h[(size_t)d0 * GC + f];
        acc += m1 * h[(size_t)d1 * GC + f];
        acc += m2 * h[(size_t)d2 * GC + f];
        acc += m3 * h[(size_t)d3 * GC + f];
    }
    acc += __shfl_xor(acc, 32, 64);
    float agg = ci ? acc / (float)ci : 0.f;
    float hv = h[(size_t)i * GC + f];
    if (half == 0) { sh[w][f] = hv; sh[w][32 + f] = agg; }
    __syncthreads();
    int c = lane;
    float hid = 0.f;
    if (c < 16) {
        hid = bl[c] + br[c];
        #pragma unroll
        for (int ff = 0; ff < 32; ++ff)
            hid += sh[w][ff] * Wl[ff * 16 + c] + sh[w][32 + ff] * Wr[ff * 16 + c];
        hid = fmaxf(hid, 0.f);
    }
    float n2 = hid * hid;
    n2 += __shfl_xor(n2, 1, 64);
    n2 += __shfl_xor(n2, 2, 64);
    n2 += __shfl_xor(n2, 4, 64);
    n2 += __shfl_xor(n2, 8, 64);
    float o = hid / (sqrtf(n2) + 1e-6f);
    if (c < 16) so[w][c] = o;
    __syncthreads();
    float logit = -INFINITY;
    if (lane < 7) {
        logit = b3[lane];
        #pragma unroll
        for (int cc = 0; cc < 16; ++cc) logit += so[w][cc] * W3[cc * 7 + lane];
    }
    float m = logit;
    m = fmaxf(m, __shfl_xor(m, 1, 64));
    m = fmaxf(m, __shfl_xor(m, 2, 64));
    m = fmaxf(m, __shfl_xor(m, 4, 64));
    float e = expf(logit - m);
    float s = e;
    s += __shfl_xor(s, 1, 64);
    s += __shfl_xor(s, 2, 64);
    s += __shfl_xor(s, 4, 64);
    if (lane < 7) out[(size_t)i * 7 + lane] = e / s;
}

extern "C" void kernel_launch(void* const* d_in, const int* in_sizes, int n_in,
                              void* d_out, int out_size, void* d_ws, size_t ws_size,
                              hipStream_t stream) {
    const float* x  = (const float*)d_in[0];
    const int*   ei = (const int*)d_in[1];
    const float* W1 = (const float*)d_in[2];
    const float* b1 = (const float*)d_in[3];
    const float* Wl = (const float*)d_in[4];
    const float* bl = (const float*)d_in[5];
    const float* Wr = (const float*)d_in[6];
    const float* br = (const float*)d_in[7];
    const float* W3 = (const float*)d_in[8];
    const float* b3 = (const float*)d_in[9];
    float* out = (float*)d_out;

    char* ws = (char*)d_ws;
    const size_t S = (size_t)GN * GC * 4;                  // 1.57 MB
    float*    xw   = (float*)(ws);
    unsigned* cnt  = (unsigned*)(ws + S);
    unsigned* deg  = cnt + GN;
    float*    h    = (float*)(deg + GN);
    unsigned* adjF = (unsigned*)((char*)h + S);            // GN*CAP*4 = 3 MB
    unsigned short* Whb = (unsigned short*)((char*)adjF + (size_t)GN * CAP * 4);
    unsigned short* Wlb = Whb + (size_t)NGRP * GC * 8;     // 98304 B each

    prep_kernel<<<PACKB + ZEROB, 256, 0, stream>>>(W1, cnt, Whb, Wlb);
    fused_kernel<<<GEMMB + EDGEB, 256, 0, stream>>>(x, ei, Whb, Wlb, xw, cnt, deg, adjF);
    gcn_kernel<<<GN / 4, 256, 0, stream>>>(xw, deg, cnt, adjF, b1, h);
    sage_kernel<<<GN / 4, 256, 0, stream>>>(h, cnt, adjF, Wl, bl, Wr, br, W3, b3, out);
}